// Round 6
// baseline (271.295 us; speedup 1.0000x reference)
//
#include <hip/hip_runtime.h>
#include <hip/hip_fp16.h>
#include <math.h>

typedef __attribute__((ext_vector_type(8)))  short short8;
typedef __attribute__((ext_vector_type(16))) float f32x16;

#define NPLANE 48
#define H 512
#define W 512
#define TH 21
#define OH 492
#define OW 492
#define EPSF 1e-8f

#define STRIDE 168   // LDS row stride in shorts (160 staged cols + pad)
#define SEG_ROWS 84  // 64 output rows + 20 halo

// d_ws layout (bytes) — ~27.4 MB:
//   [0)        B_corr : 48 * 21 * 4 * 512 bf16 = 4,128,768 B (frag-swizzled)
//   [4194304)  N      : 48 * 492 * 492 fp16 = 23.24 MB  (1/(sd+eps))
#define N_HOFF_BYTES 4194304u

__device__ inline unsigned short f2bf(float f) {
    unsigned u = __float_as_uint(f);
    return (unsigned short)((u + 0x7FFFu + ((u >> 16) & 1u)) >> 16);
}

#if defined(__has_builtin)
#if __has_builtin(__builtin_amdgcn_cvt_pk_bf16_f32)
#define HAVE_CVT_PK_BF16 1
#endif
#endif

#ifdef HAVE_CVT_PK_BF16
typedef __attribute__((ext_vector_type(2))) __bf16 bf16x2;
__device__ inline unsigned pack2bf(float a, float b) {
    bf16x2 r = __builtin_amdgcn_cvt_pk_bf16_f32(a, b);
    return *(unsigned*)&r;
}
#else
__device__ inline unsigned pack2bf(float a, float b) {
    return (unsigned)f2bf(a) | ((unsigned)f2bf(b) << 16);
}
#endif

// ---------------------------------------------------------------------------
// K0: template z-norm (/441 folded) -> Toeplitz B fragments (frag-swizzled:
// main kernel's B load is lane*8 contiguous bf16).
// B[k][n] = t_hat[u][16s + k - n], k = (lane>>5)*8 + j, n = lane&31.
// ---------------------------------------------------------------------------
__global__ void build_b_kernel(const float* __restrict__ tpl,
                               unsigned short* __restrict__ ws16) {
    __shared__ float sm[2];
    const int plane = blockIdx.x;
    const float* t = tpl + plane * 441;
    const int tid = threadIdx.x;
    if (tid < 64) {
        float s = 0.f, s2 = 0.f;
        for (int k = tid; k < 441; k += 64) {
            float x = t[k];
            s += x; s2 += x * x;
        }
#pragma unroll
        for (int o = 32; o >= 1; o >>= 1) {
            s  += __shfl_down(s, o);
            s2 += __shfl_down(s2, o);
        }
        if (tid == 0) {
            float mean = s / 441.f;
            float var = fmaxf(s2 / 441.f - mean * mean, 0.f);
            sm[0] = mean;
            sm[1] = 1.f / ((sqrtf(var) + EPSF) * 441.f);
        }
    }
    __syncthreads();
    const float mean = sm[0], scale = sm[1];

    unsigned short* bc = ws16 + (size_t)plane * 43008;
    for (int i = tid; i < 43008; i += 256) {
        int j = i & 7, lane = (i >> 3) & 63, s = (i >> 9) & 3, u = i >> 11;
        int k = ((lane >> 5) << 3) + j, n = lane & 31;
        int v = 16 * s + k - n;
        float val = (v >= 0 && v < TH) ? (t[u * 21 + v] - mean) * scale : 0.f;
        bc[i] = f2bf(val);
    }
}

// ---------------------------------------------------------------------------
// K1: local-std normalizer N = 1/(sd+eps) as fp16, separable box filter.
// Block = 64 rows x 192 cols of output. Phase 1: 212 column workers stream
// input (coalesced), keep fp32 running 21-sums (S, Q), pack fp16x2 into LDS.
// Phase 2: 256 threads = 64 rows x 4 col-segments, horizontal 21-slide,
// write N fp16 (paired u32 stores).
// ---------------------------------------------------------------------------
__global__ __launch_bounds__(256, 2) void nstd_kernel(
    const float* __restrict__ in, __half* __restrict__ N) {
    __shared__ unsigned vb[64 * 216];  // fp16x2 (S,Q) per (row, col)

    const int plane = blockIdx.z;
    const int x0 = blockIdx.x * 192;
    const int y0 = blockIdx.y * 64;
    const int tid = threadIdx.x;
    const float* src = in + (size_t)plane * H * W;

    if (tid < 212) {
        const int x = x0 + tid;
        const bool ok = (x < W);
        float s = 0.f, q = 0.f;
#pragma unroll
        for (int r = 0; r < 20; ++r) {  // y0+r <= 467 < H always
            float v = ok ? src[(y0 + r) * W + x] : 0.f;
            s += v;
            q = fmaf(v, v, q);
        }
        for (int i = 0; i < 64; ++i) {
            int gy = y0 + 20 + i;
            float v = (ok && gy < H) ? src[gy * W + x] : 0.f;
            s += v;
            q = fmaf(v, v, q);
            __half2 p;
            p.x = __float2half(s);
            p.y = __float2half(q);
            vb[i * 216 + tid] = *(unsigned*)&p;
            float o = ok ? src[(y0 + i) * W + x] : 0.f;  // y0+i <= 511
            s -= o;
            q = fmaf(-o, o, q);
        }
    }
    __syncthreads();

    const int row = tid >> 2;
    const int sg = tid & 3;
    const int base = row * 216 + sg * 48;
    const int gy = y0 + row;
    const float invn = 1.f / 441.f;
    __half* nrow = N + ((size_t)plane * OH + gy) * OW;

    float S = 0.f, Q = 0.f;
#pragma unroll
    for (int k = 0; k < 20; ++k) {
        __half2 p = *(__half2*)&vb[base + k];
        S += __half2float(p.x);
        Q += __half2float(p.y);
    }
    float hold = 0.f;
    for (int j = 0; j < 48; ++j) {
        __half2 p = *(__half2*)&vb[base + j + 20];
        S += __half2float(p.x);
        Q += __half2float(p.y);
        float mean = S * invn;
        float msq = Q * invn;
        float sd = __builtin_amdgcn_sqrtf(msq - mean * mean + EPSF);
        float inv = __builtin_amdgcn_rcpf(sd + EPSF);
        int gx = x0 + sg * 48 + j;
        if ((j & 1) == 0) {
            hold = inv;
        } else if (gy < OH) {
            if (gx < OW) {  // paired store (gx-1, gx), both in range
                __half2 o;
                o.x = __float2half(hold);
                o.y = __float2half(inv);
                *(__half2*)&nrow[gx - 1] = o;
            } else if (gx - 1 < OW) {
                nrow[gx - 1] = __float2half(hold);
            }
        }
        __half2 d = *(__half2*)&vb[base + j];
        S -= __half2float(d.x);
        Q -= __half2float(d.y);
    }
}

// ---------------------------------------------------------------------------
// K2: main MFMA kernel. Block = 64x128 outputs, 4 waves x two 32x32 tiles.
// Phases: [stage 84x160 fp32->bf16 LDS] -> ONE barrier ->
//         [corr K-loop: 21u x (6 ds_read_b128 + 4 global B + 8 MFMA)] ->
//         [epilogue: load N fp16, out = acc*N]
// LDS = 84*168*2 = 28.2 KB -> 5 blocks/CU (20 waves; was 3 blocks/4 barriers).
// A cols 148..159 are garbage-free (staged zeros) and hit zero B band.
// ---------------------------------------------------------------------------
__global__ __launch_bounds__(256, 5) void ncc_mfma_kernel(
    const float* __restrict__ in, const unsigned short* __restrict__ ws16,
    const __half* __restrict__ N, float* __restrict__ out) {
    __shared__ short seg[SEG_ROWS * STRIDE];

    const int plane = blockIdx.z;
    const int x0 = blockIdx.x * 128;
    const int y0 = blockIdx.y * 64;
    const int tid = threadIdx.x;
    const int lane = tid & 63;
    const int tr = (tid >> 6) & 1;   // tile-row of this wave
    const int tc = tid >> 7;         // tile-col pair of this wave
    const float* src = in + (size_t)plane * H * W;

    // ---- stage 84x160 fp32 -> bf16 into LDS ----
    for (int i = tid; i < SEG_ROWS * 20; i += 256) {
        int row = i / 20, s8 = i - row * 20;
        int gy = y0 + row, gx = x0 + s8 * 8;
        if (gy < H && gx + 7 < W) {
            float4 a = *(const float4*)(src + gy * W + gx);
            float4 b = *(const float4*)(src + gy * W + gx + 4);
            int4 p;
            p.x = (int)pack2bf(a.x, a.y);
            p.y = (int)pack2bf(a.z, a.w);
            p.z = (int)pack2bf(b.x, b.y);
            p.w = (int)pack2bf(b.z, b.w);
            *(int4*)&seg[row * STRIDE + s8 * 8] = p;
        } else {
            short8 val;
#pragma unroll
            for (int e = 0; e < 8; ++e) {
                float xv = (gy < H && gx + e < W) ? src[gy * W + gx + e] : 0.f;
                val[e] = (short)f2bf(xv);
            }
            *(short8*)&seg[row * STRIDE + s8 * 8] = val;
        }
    }
    __syncthreads();

    const int m = lane & 31;
    const int half = lane >> 5;
    const int abase = (tr * 32 + m) * STRIDE + tc * 64 + half * 8;
    const unsigned short* bc = ws16 + (size_t)plane * 43008 + lane * 8;

    f32x16 acc[2];
#pragma unroll
    for (int t = 0; t < 2; ++t)
#pragma unroll
        for (int e = 0; e < 16; ++e) acc[t][e] = 0.f;

#pragma unroll
    for (int u = 0; u < TH; ++u) {
        short8 bf[4];
#pragma unroll
        for (int s = 0; s < 4; ++s)
            bf[s] = *(const short8*)(bc + (u * 4 + s) * 512);
        short8 af[6];
#pragma unroll
        for (int g = 0; g < 6; ++g)
            af[g] = *(const short8*)&seg[abase + u * STRIDE + g * 16];
#pragma unroll
        for (int t = 0; t < 2; ++t)
#pragma unroll
            for (int s = 0; s < 4; ++s)
                acc[t] = __builtin_amdgcn_mfma_f32_32x32x16_bf16(
                    af[2 * t + s], bf[s], acc[t], 0, 0, 0);
    }

    // ---- epilogue: out = acc * N (fp16 normalizer, precomputed) ----
    const __half* Np = N + (size_t)plane * OH * OW;
    float* outp = out + (size_t)plane * OH * OW;
#pragma unroll
    for (int t = 0; t < 2; ++t) {
        const int gx = x0 + tc * 64 + t * 32 + (lane & 31);
        if (gx < OW) {
#pragma unroll
            for (int r = 0; r < 16; ++r) {
                int gy = y0 + tr * 32 + (r & 3) + ((r >> 2) << 3) + half * 4;
                if (gy < OH) {
                    size_t idx = (size_t)gy * OW + gx;
                    outp[idx] = acc[t][r] * __half2float(Np[idx]);
                }
            }
        }
    }
}

extern "C" void kernel_launch(void* const* d_in, const int* in_sizes, int n_in,
                              void* d_out, int out_size, void* d_ws,
                              size_t ws_size, hipStream_t stream) {
    const float* inputs = (const float*)d_in[0];
    const float* tmpl = (const float*)d_in[1];
    float* out = (float*)d_out;
    unsigned short* ws16 = (unsigned short*)d_ws;
    __half* Nbuf = (__half*)((char*)d_ws + N_HOFF_BYTES);

    build_b_kernel<<<NPLANE, 256, 0, stream>>>(tmpl, ws16);
    nstd_kernel<<<dim3(3, 8, NPLANE), 256, 0, stream>>>(inputs, Nbuf);
    ncc_mfma_kernel<<<dim3(4, 8, NPLANE), 256, 0, stream>>>(inputs, ws16, Nbuf,
                                                            out);
}